// Round 6
// baseline (2026.607 us; speedup 1.0000x reference)
//
#include <hip/hip_runtime.h>

namespace {

typedef float v2f __attribute__((ext_vector_type(2)));
typedef float v4f __attribute__((ext_vector_type(4)));

constexpr int H  = 64;    // hidden
constexpr int G4 = 256;   // 4*H gates
constexpr int T  = 256;   // seq len
constexpr int GB = 4;     // batch elems per block

__device__ __forceinline__ float frcp(float x) { return __builtin_amdgcn_rcpf(x); }
__device__ __forceinline__ float sgm(float x) { return frcp(1.f + __expf(-x)); }
__device__ __forceinline__ float ftanh(float x) {
  const float e = __expf(-2.f * x);
  return (1.f - e) * frcp(1.f + e);
}

// acc[g] (v2f over k-pairs) += W[j][kb..kb+32) . h[g][kb..kb+32)
// weights in registers, h broadcast (wave-uniform address) from LDS.
__device__ __forceinline__ void accum(const v4f (&wm)[8], const float (*h)[H], int kb,
                                      v2f (&acc)[GB]) {
#pragma unroll
  for (int r = 0; r < 8; ++r) {
    const v2f wl = {wm[r][0], wm[r][1]};
    const v2f wh = {wm[r][2], wm[r][3]};
#pragma unroll
    for (int g = 0; g < GB; ++g) {
      const v4f hv = *(const v4f*)&h[g][kb + 4 * r];
      const v2f hl = {hv[0], hv[1]};
      const v2f hh = {hv[2], hv[3]};
      acc[g] = __builtin_elementwise_fma(wl, hl, acc[g]);
      acc[g] = __builtin_elementwise_fma(wh, hh, acc[g]);
    }
  }
}

__global__ __launch_bounds__(512, 1) void seq2seq_kernel(
    const float* __restrict__ enc_x, const float* __restrict__ dec_x,
    const float* __restrict__ eWih0, const float* __restrict__ eWhh0,
    const float* __restrict__ eb0,
    const float* __restrict__ eWih1, const float* __restrict__ eWhh1,
    const float* __restrict__ eb1,
    const float* __restrict__ eWih2, const float* __restrict__ eWhh2,
    const float* __restrict__ eb2,
    const float* __restrict__ dWih0, const float* __restrict__ dWhh0,
    const float* __restrict__ db0,
    const float* __restrict__ dWih1, const float* __restrict__ dWhh1,
    const float* __restrict__ db1,
    const float* __restrict__ dWih2, const float* __restrict__ dWhh2,
    const float* __restrict__ db2,
    const float* __restrict__ fcW, const float* __restrict__ fcb,
    float* __restrict__ out) {
  __shared__ float hs[3][GB][H];    // 3 KB  hidden state [layer][g][k]
  __shared__ float yp[GB][H];       // 1 KB  decoder feedback
  __shared__ float xs[2][GB][T];    // 8 KB  staged enc_x / dec_x
  __shared__ float zp[2][GB][G4];   // 8 KB  z partials [k-half][g][gate row]
  __shared__ float bias[6][G4];     // 6 KB

  const int tid = threadIdx.x;
  const int j  = tid & 255;  // gate row (0..255): [i|f|g|o] x 64
  const int q  = tid >> 8;   // k-half (wave-uniform)
  const int kb = q * 32;
  const int g2 = (tid >> 6) & 3, u = tid & 63;  // update mapping (tid<256)
  const int b0 = blockIdx.x * GB;

  // ---- stage x, biases; zero state ----
  for (int i = tid; i < GB * T; i += 512) {
    ((float*)xs[0])[i] = enc_x[b0 * T + i];
    ((float*)xs[1])[i] = dec_x[b0 * T + i];
  }
  if (tid < 256) {
    bias[0][tid] = eb0[tid]; bias[1][tid] = eb1[tid]; bias[2][tid] = eb2[tid];
    bias[3][tid] = db0[tid]; bias[4][tid] = db1[tid]; bias[5][tid] = db2[tid];
  }
  for (int i = tid; i < 3 * GB * H; i += 512) ((float*)hs)[i] = 0.f;
  for (int i = tid; i < GB * H; i += 512) ((float*)yp)[i] = 0.f;

  float cr0 = 0.f, cr1 = 0.f, cr2 = 0.f;  // cell state (update threads)
  const float fcw = fcW[u];
  const float fcbv = fcb[0];

  // ---- weights -> registers: 6 mats x 32 k-floats = 192 floats/thread ----
  v4f w[6][8];
#define LDW(M, W, LD, OFF)                                                   \
  {                                                                          \
    const float* s = (W) + j * (LD) + (OFF) + kb;                            \
    _Pragma("unroll") for (int r = 0; r < 8; ++r)                            \
        w[M][r] = *(const v4f*)(s + 4 * r);                                  \
  }
#define LDW_U(M, W, LD, OFF)  /* element loads (4B-aligned source) */        \
  {                                                                          \
    const float* s = (W) + j * (LD) + (OFF) + kb;                            \
    _Pragma("unroll") for (int r = 0; r < 8; ++r)                            \
        w[M][r] = (v4f){s[4 * r], s[4 * r + 1], s[4 * r + 2], s[4 * r + 3]}; \
  }
// Opacity barrier: make weight values opaque so the compiler can neither
// re-load them from global (restream) nor rematerialize -- must keep in VGPRs.
#define OPQ(N)                                                               \
  _Pragma("unroll") for (int m = 0; m < (N); ++m)                            \
      _Pragma("unroll") for (int r = 0; r < 8; ++r)                          \
          asm volatile("" : "+v"(w[m][r]));

  LDW(0, eWhh0, 64, 0)
  LDW(1, eWih1, 64, 0)
  LDW(2, eWhh1, 64, 0)
  LDW(3, eWih2, 64, 0)
  LDW(4, eWhh2, 64, 0)
  float xw = (q == 0) ? eWih0[j] : 0.f;  // I=1 input column
  OPQ(5)
  asm volatile("" : "+v"(xw));

  __syncthreads();

#define ZSTORE                                                               \
  _Pragma("unroll") for (int g = 0; g < GB; ++g)                             \
      zp[q][g][j] = acc[g][0] + acc[g][1];

#define ACLR                                                                 \
  v2f acc[GB];                                                               \
  _Pragma("unroll") for (int g = 0; g < GB; ++g) acc[g] = (v2f)(0.f);

// barrier -> gate reduction -> (h,c) update for layer L, bias row BROW.
#define ZUPD(L, BROW, EXTRA)                                                 \
  __syncthreads();                                                           \
  if (tid < 256) {                                                           \
    float z[4];                                                              \
    _Pragma("unroll") for (int m = 0; m < 4; ++m)                            \
        z[m] = bias[BROW][m * 64 + u] + zp[0][g2][m * 64 + u] +              \
               zp[1][g2][m * 64 + u];                                        \
    const float ii = sgm(z[0]), ff = sgm(z[1]);                              \
    const float gg = ftanh(z[2]), oo = sgm(z[3]);                            \
    const float cn = ff * cr##L + ii * gg;                                   \
    cr##L = cn;                                                              \
    const float hn = oo * ftanh(cn);                                         \
    hs[L][g2][u] = hn;                                                       \
    EXTRA                                                                    \
  }                                                                          \
  __syncthreads();

  // ---------------- Encoder ----------------
  for (int t = 0; t < T; ++t) {
    {
      ACLR
      accum(w[0], hs[0], kb, acc);
      if (q == 0) {
#pragma unroll
        for (int g = 0; g < GB; ++g) acc[g][0] += xw * xs[0][g][t];
      }
      ZSTORE
      ZUPD(0, 0, )
    }
    {
      ACLR
      accum(w[1], hs[0], kb, acc);
      accum(w[2], hs[1], kb, acc);
      ZSTORE
      ZUPD(1, 1, )
    }
    {
      ACLR
      accum(w[3], hs[1], kb, acc);
      accum(w[4], hs[2], kb, acc);
      ZSTORE
      ZUPD(2, 2, )
    }
  }

  // ---- decoder weights -> registers (enc weights dead; regs reused) ----
  LDW_U(0, dWih0, 65, 1)  // y_prev columns of [256 x 65]
  LDW(1, dWhh0, 64, 0)
  LDW(2, dWih1, 64, 0)
  LDW(3, dWhh1, 64, 0)
  LDW(4, dWih2, 64, 0)
  LDW(5, dWhh2, 64, 0)
  xw = (q == 0) ? dWih0[j * 65] : 0.f;  // x column of concat(x, y_prev)
  OPQ(6)
  asm volatile("" : "+v"(xw));

  // ---------------- Decoder ----------------
  for (int t = 0; t < T; ++t) {
    {
      ACLR
      accum(w[0], yp, kb, acc);
      accum(w[1], hs[0], kb, acc);
      if (q == 0) {
#pragma unroll
        for (int g = 0; g < GB; ++g) acc[g][0] += xw * xs[1][g][t];
      }
      ZSTORE
      ZUPD(0, 3, )
    }
    {
      ACLR
      accum(w[2], hs[0], kb, acc);
      accum(w[3], hs[1], kb, acc);
      ZSTORE
      ZUPD(1, 4, )
    }
    {
      ACLR
      accum(w[4], hs[1], kb, acc);
      accum(w[5], hs[2], kb, acc);
      ZSTORE
      ZUPD(2, 5, {
        yp[g2][u] = hn;
        float pr = hn * fcw;
        _Pragma("unroll") for (int o = 32; o > 0; o >>= 1)
            pr += __shfl_down(pr, o, 64);
        if (u == 0) out[(b0 + g2) * T + t] = pr + fcbv;
      })
    }
  }
#undef ZUPD
#undef ZSTORE
#undef ACLR
#undef OPQ
#undef LDW
#undef LDW_U
}

}  // namespace

extern "C" void kernel_launch(void* const* d_in, const int* in_sizes, int n_in,
                              void* d_out, int out_size, void* d_ws, size_t ws_size,
                              hipStream_t stream) {
  const float* enc_x = (const float*)d_in[0];
  const float* dec_x = (const float*)d_in[1];
  const float* eWih0 = (const float*)d_in[2];
  const float* eWhh0 = (const float*)d_in[3];
  const float* eb0   = (const float*)d_in[4];
  const float* eWih1 = (const float*)d_in[5];
  const float* eWhh1 = (const float*)d_in[6];
  const float* eb1   = (const float*)d_in[7];
  const float* eWih2 = (const float*)d_in[8];
  const float* eWhh2 = (const float*)d_in[9];
  const float* eb2   = (const float*)d_in[10];
  const float* dWih0 = (const float*)d_in[11];
  const float* dWhh0 = (const float*)d_in[12];
  const float* db0   = (const float*)d_in[13];
  const float* dWih1 = (const float*)d_in[14];
  const float* dWhh1 = (const float*)d_in[15];
  const float* db1   = (const float*)d_in[16];
  const float* dWih2 = (const float*)d_in[17];
  const float* dWhh2 = (const float*)d_in[18];
  const float* db2   = (const float*)d_in[19];
  const float* fcW   = (const float*)d_in[20];
  const float* fcb   = (const float*)d_in[21];
  float* out = (float*)d_out;

  seq2seq_kernel<<<dim3(256), dim3(512), 0, stream>>>(
      enc_x, dec_x, eWih0, eWhh0, eb0, eWih1, eWhh1, eb1, eWih2, eWhh2, eb2,
      dWih0, dWhh0, db0, dWih1, dWhh1, db1, dWih2, dWhh2, db2, fcW, fcb, out);
}

// Round 7
// 1925.266 us; speedup vs baseline: 1.0526x; 1.0526x over previous
//
#include <hip/hip_runtime.h>

namespace {

typedef float v2f __attribute__((ext_vector_type(2)));
typedef float v4f __attribute__((ext_vector_type(4)));

constexpr int H  = 64;    // hidden
constexpr int G4 = 256;   // 4*H gates
constexpr int T  = 256;   // seq len
constexpr int GB = 4;     // batch elems per block

__device__ __forceinline__ float frcp(float x) { return __builtin_amdgcn_rcpf(x); }
__device__ __forceinline__ float sgm(float x) { return frcp(1.f + __expf(-x)); }
__device__ __forceinline__ float ftanh(float x) {
  const float e = __expf(-2.f * x);
  return (1.f - e) * frcp(1.f + e);
}

// acc[i][g] += W[4qd+i][kb..kb+8) . h[g][kb..kb+8)
// One b128 h-read feeds 8 pk-fma (4 rows x 2) -> LDS:VALU inst ratio 1:8.
__device__ __forceinline__ void accum(const v4f (&wm)[4][2], const float (*h)[H], int kb,
                                      v2f (&acc)[4][GB]) {
#pragma unroll
  for (int g = 0; g < GB; ++g) {
    const v4f a = *(const v4f*)&h[g][kb];
    const v4f b = *(const v4f*)&h[g][kb + 4];
    const v2f p0 = {a[0], a[1]}, p1 = {a[2], a[3]};
    const v2f p2 = {b[0], b[1]}, p3 = {b[2], b[3]};
#pragma unroll
    for (int i = 0; i < 4; ++i) {
      acc[i][g] = __builtin_elementwise_fma((v2f){wm[i][0][0], wm[i][0][1]}, p0, acc[i][g]);
      acc[i][g] = __builtin_elementwise_fma((v2f){wm[i][0][2], wm[i][0][3]}, p1, acc[i][g]);
      acc[i][g] = __builtin_elementwise_fma((v2f){wm[i][1][0], wm[i][1][1]}, p2, acc[i][g]);
      acc[i][g] = __builtin_elementwise_fma((v2f){wm[i][1][2], wm[i][1][3]}, p3, acc[i][g]);
    }
  }
}

__global__ __attribute__((amdgpu_flat_work_group_size(512, 512)))
__attribute__((amdgpu_waves_per_eu(2, 2))) void seq2seq_kernel(
    const float* __restrict__ enc_x, const float* __restrict__ dec_x,
    const float* __restrict__ eWih0, const float* __restrict__ eWhh0,
    const float* __restrict__ eb0,
    const float* __restrict__ eWih1, const float* __restrict__ eWhh1,
    const float* __restrict__ eb1,
    const float* __restrict__ eWih2, const float* __restrict__ eWhh2,
    const float* __restrict__ eb2,
    const float* __restrict__ dWih0, const float* __restrict__ dWhh0,
    const float* __restrict__ db0,
    const float* __restrict__ dWih1, const float* __restrict__ dWhh1,
    const float* __restrict__ db1,
    const float* __restrict__ dWih2, const float* __restrict__ dWhh2,
    const float* __restrict__ db2,
    const float* __restrict__ fcW, const float* __restrict__ fcb,
    float* __restrict__ out) {
  __shared__ float hs[3][GB][H];   // 3 KB   hidden state [layer][g][k]
  __shared__ float yp[GB][H];      // 1 KB   decoder feedback
  __shared__ float xs[2][GB][T];   // 8 KB   staged enc_x / dec_x
  __shared__ float zp[8][GB][G4];  // 32 KB  z partials [k-octet][g][gate row]
  __shared__ float bias[6][G4];    // 6 KB

  const int tid = threadIdx.x;
  const int wave = tid >> 6, lane = tid & 63;
  // Unique (row-quad, k-octet) tiling of each [256 x 64] matrix over 512 threads.
  const int oc = ((lane >> 5) & 1) | ((wave & 3) << 1);  // k-octet 0..7
  const int qd = (lane & 31) | ((wave >> 2) << 5);       // row-quad 0..63
  const int kb = oc * 8;
  const int r0 = qd * 4;                                  // first owned gate row
  const int g2 = (tid >> 6) & 3, u = tid & 63;            // update mapping (tid<256)
  const int b0 = blockIdx.x * GB;

  // ---- stage x, biases; zero state ----
  for (int i = tid; i < GB * T; i += 512) {
    ((float*)xs[0])[i] = enc_x[b0 * T + i];
    ((float*)xs[1])[i] = dec_x[b0 * T + i];
  }
  if (tid < 256) {
    bias[0][tid] = eb0[tid]; bias[1][tid] = eb1[tid]; bias[2][tid] = eb2[tid];
    bias[3][tid] = db0[tid]; bias[4][tid] = db1[tid]; bias[5][tid] = db2[tid];
  }
  for (int i = tid; i < 3 * GB * H; i += 512) ((float*)hs)[i] = 0.f;
  for (int i = tid; i < GB * H; i += 512) ((float*)yp)[i] = 0.f;

  float cr0 = 0.f, cr1 = 0.f, cr2 = 0.f;  // cell state (update threads)
  const float fcw = fcW[u];
  const float fcbv = fcb[0];

  // ---- weights -> registers: 6 mats x 4 rows x 8 k = 192 floats/thread ----
  v4f w[6][4][2];
#define LDW(M, W, LD, OFF)                                                   \
  {                                                                          \
    _Pragma("unroll") for (int i = 0; i < 4; ++i) {                          \
      const float* s = (W) + (r0 + i) * (LD) + (OFF) + kb;                   \
      w[M][i][0] = *(const v4f*)s;                                           \
      w[M][i][1] = *(const v4f*)(s + 4);                                     \
    }                                                                        \
  }
#define LDW_U(M, W, LD, OFF) /* element loads (4B-aligned source) */         \
  {                                                                          \
    _Pragma("unroll") for (int i = 0; i < 4; ++i) {                          \
      const float* s = (W) + (r0 + i) * (LD) + (OFF) + kb;                   \
      w[M][i][0] = (v4f){s[0], s[1], s[2], s[3]};                            \
      w[M][i][1] = (v4f){s[4], s[5], s[6], s[7]};                            \
    }                                                                        \
  }
// Opacity barrier: weights become opaque values -- compiler can't restream
// from global or rematerialize; must keep them resident.
#define OPQ(N)                                                               \
  _Pragma("unroll") for (int m = 0; m < (N); ++m)                            \
      _Pragma("unroll") for (int i = 0; i < 4; ++i) {                        \
        asm volatile("" : "+v"(w[m][i][0]));                                 \
        asm volatile("" : "+v"(w[m][i][1]));                                 \
      }

  LDW(0, eWhh0, 64, 0)
  LDW(1, eWih1, 64, 0)
  LDW(2, eWhh1, 64, 0)
  LDW(3, eWih2, 64, 0)
  LDW(4, eWhh2, 64, 0)
  float xw[4];
#pragma unroll
  for (int i = 0; i < 4; ++i) xw[i] = eWih0[r0 + i];  // I=1 input column
  OPQ(5)

  __syncthreads();

// z partials: one b128 store per batch elem (4 consecutive rows).
#define ZSTORE                                                               \
  {                                                                          \
    _Pragma("unroll") for (int g = 0; g < GB; ++g) {                         \
      v4f zs;                                                                \
      zs[0] = acc[0][g][0] + acc[0][g][1];                                   \
      zs[1] = acc[1][g][0] + acc[1][g][1];                                   \
      zs[2] = acc[2][g][0] + acc[2][g][1];                                   \
      zs[3] = acc[3][g][0] + acc[3][g][1];                                   \
      *(v4f*)&zp[oc][g][r0] = zs;                                            \
    }                                                                        \
  }

#define ACLR                                                                 \
  v2f acc[4][GB];                                                            \
  _Pragma("unroll") for (int i = 0; i < 4; ++i)                              \
      _Pragma("unroll") for (int g = 0; g < GB; ++g) acc[i][g] = (v2f)(0.f);

// barrier -> gate reduction (8 k-octet partials) -> (h,c) update.
#define ZUPD(L, BROW, EXTRA)                                                 \
  __syncthreads();                                                           \
  if (tid < 256) {                                                           \
    float z[4];                                                              \
    _Pragma("unroll") for (int m = 0; m < 4; ++m)                            \
        z[m] = bias[BROW][m * 64 + u];                                       \
    _Pragma("unroll") for (int o8 = 0; o8 < 8; ++o8)                         \
        _Pragma("unroll") for (int m = 0; m < 4; ++m)                        \
            z[m] += zp[o8][g2][m * 64 + u];                                  \
    const float ii = sgm(z[0]), ff = sgm(z[1]);                              \
    const float gg = ftanh(z[2]), oo = sgm(z[3]);                            \
    const float cn = ff * cr##L + ii * gg;                                   \
    cr##L = cn;                                                              \
    const float hn = oo * ftanh(cn);                                         \
    hs[L][g2][u] = hn;                                                       \
    EXTRA                                                                    \
  }                                                                          \
  __syncthreads();

  // ---------------- Encoder ----------------
#pragma clang loop unroll(disable)
  for (int t = 0; t < T; ++t) {
    {
      ACLR
      accum(w[0], hs[0], kb, acc);
      if (oc == 0) {  // fold x * Wih0 column exactly once
#pragma unroll
        for (int g = 0; g < GB; ++g) {
          const float xv = xs[0][g][t];
#pragma unroll
          for (int i = 0; i < 4; ++i) acc[i][g][0] += xw[i] * xv;
        }
      }
      ZSTORE
      ZUPD(0, 0, )
    }
    {
      ACLR
      accum(w[1], hs[0], kb, acc);
      accum(w[2], hs[1], kb, acc);
      ZSTORE
      ZUPD(1, 1, )
    }
    {
      ACLR
      accum(w[3], hs[1], kb, acc);
      accum(w[4], hs[2], kb, acc);
      ZSTORE
      ZUPD(2, 2, )
    }
  }

  // ---- decoder weights -> registers (enc weights dead; regs reused) ----
  LDW_U(0, dWih0, 65, 1)  // y_prev columns of [256 x 65]
  LDW(1, dWhh0, 64, 0)
  LDW(2, dWih1, 64, 0)
  LDW(3, dWhh1, 64, 0)
  LDW(4, dWih2, 64, 0)
  LDW(5, dWhh2, 64, 0)
#pragma unroll
  for (int i = 0; i < 4; ++i) xw[i] = dWih0[(r0 + i) * 65];  // x column
  OPQ(6)

  // ---------------- Decoder ----------------
#pragma clang loop unroll(disable)
  for (int t = 0; t < T; ++t) {
    {
      ACLR
      accum(w[0], yp, kb, acc);
      accum(w[1], hs[0], kb, acc);
      if (oc == 0) {
#pragma unroll
        for (int g = 0; g < GB; ++g) {
          const float xv = xs[1][g][t];
#pragma unroll
          for (int i = 0; i < 4; ++i) acc[i][g][0] += xw[i] * xv;
        }
      }
      ZSTORE
      ZUPD(0, 3, )
    }
    {
      ACLR
      accum(w[2], hs[0], kb, acc);
      accum(w[3], hs[1], kb, acc);
      ZSTORE
      ZUPD(1, 4, )
    }
    {
      ACLR
      accum(w[4], hs[1], kb, acc);
      accum(w[5], hs[2], kb, acc);
      ZSTORE
      ZUPD(2, 5, {
        yp[g2][u] = hn;
        float pr = hn * fcw;
        _Pragma("unroll") for (int o = 32; o > 0; o >>= 1)
            pr += __shfl_down(pr, o, 64);
        if (u == 0) out[(b0 + g2) * T + t] = pr + fcbv;
      })
    }
  }
#undef ZUPD
#undef ZSTORE
#undef ACLR
#undef OPQ
#undef LDW
#undef LDW_U
}

}  // namespace

extern "C" void kernel_launch(void* const* d_in, const int* in_sizes, int n_in,
                              void* d_out, int out_size, void* d_ws, size_t ws_size,
                              hipStream_t stream) {
  const float* enc_x = (const float*)d_in[0];
  const float* dec_x = (const float*)d_in[1];
  const float* eWih0 = (const float*)d_in[2];
  const float* eWhh0 = (const float*)d_in[3];
  const float* eb0   = (const float*)d_in[4];
  const float* eWih1 = (const float*)d_in[5];
  const float* eWhh1 = (const float*)d_in[6];
  const float* eb1   = (const float*)d_in[7];
  const float* eWih2 = (const float*)d_in[8];
  const float* eWhh2 = (const float*)d_in[9];
  const float* eb2   = (const float*)d_in[10];
  const float* dWih0 = (const float*)d_in[11];
  const float* dWhh0 = (const float*)d_in[12];
  const float* db0   = (const float*)d_in[13];
  const float* dWih1 = (const float*)d_in[14];
  const float* dWhh1 = (const float*)d_in[15];
  const float* db1   = (const float*)d_in[16];
  const float* dWih2 = (const float*)d_in[17];
  const float* dWhh2 = (const float*)d_in[18];
  const float* db2   = (const float*)d_in[19];
  const float* fcW   = (const float*)d_in[20];
  const float* fcb   = (const float*)d_in[21];
  float* out = (float*)d_out;

  seq2seq_kernel<<<dim3(256), dim3(512), 0, stream>>>(
      enc_x, dec_x, eWih0, eWhh0, eb0, eWih1, eWhh1, eb1, eWih2, eWhh2, eb2,
      dWih0, dWhh0, db0, dWih1, dWhh1, db1, dWih2, dWhh2, db2, fcW, fcb, out);
}

// Round 8
// 1092.825 us; speedup vs baseline: 1.8545x; 1.7617x over previous
//
#include <hip/hip_runtime.h>

namespace {

using v4f    = __attribute__((ext_vector_type(4))) float;
using short8 = __attribute__((ext_vector_type(8))) short;

constexpr int T = 256, GB = 4;

__device__ __forceinline__ float frcp(float x) { return __builtin_amdgcn_rcpf(x); }
__device__ __forceinline__ float sgm(float x) { return frcp(1.f + __expf(-x)); }
__device__ __forceinline__ float ftanh(float x) {
  const float e = __expf(-2.f * x);
  return (1.f - e) * frcp(1.f + e);
}

__device__ __forceinline__ unsigned short f2bf(float f) {
  unsigned x = __float_as_uint(f);
  return (unsigned short)((x + 0x7FFFu + ((x >> 16) & 1u)) >> 16);
}
__device__ __forceinline__ float bf2f(unsigned short s) {
  return __uint_as_float((unsigned)s << 16);
}

// f32[8] -> (hi, lo) bf16 split fragments.
__device__ __forceinline__ void cvt8(const float* w, short8& hi, short8& lo) {
#pragma unroll
  for (int j = 0; j < 8; ++j) {
    const unsigned short h = f2bf(w[j]);
    hi[j] = (short)h;
    lo[j] = (short)f2bf(w[j] - bf2f(h));
  }
}

#define MFMA(A, B, C) __builtin_amdgcn_mfma_f32_16x16x32_bf16((A), (B), (C), 0, 0, 0)

__global__ __launch_bounds__(512, 1) void seq2seq_kernel(
    const float* __restrict__ enc_x, const float* __restrict__ dec_x,
    const float* __restrict__ eWih0, const float* __restrict__ eWhh0, const float* __restrict__ eb0,
    const float* __restrict__ eWih1, const float* __restrict__ eWhh1, const float* __restrict__ eb1,
    const float* __restrict__ eWih2, const float* __restrict__ eWhh2, const float* __restrict__ eb2,
    const float* __restrict__ dWih0, const float* __restrict__ dWhh0, const float* __restrict__ db0,
    const float* __restrict__ dWih1, const float* __restrict__ dWhh1, const float* __restrict__ db1,
    const float* __restrict__ dWih2, const float* __restrict__ dWhh2, const float* __restrict__ db2,
    const float* __restrict__ fcW, const float* __restrict__ fcb,
    float* __restrict__ out) {
  // h (+yp) stored ONLY as bf16 hi/lo in MFMA-B-friendly layout [hl][arr][col16][k 72(pad)]
  __shared__ __align__(16) unsigned short hb[2][4][16][72];  // 18.4 KB (arr: h0,h1,h2,yp)
  __shared__ float zl[GB][264];                              // 4.2 KB  z (K-complete), padded
  __shared__ float xs[2][GB][T];                             // 8 KB    staged enc_x/dec_x
  __shared__ float bias[6][256];                             // 6 KB

  const int tid = threadIdx.x;
  const int w = tid >> 6, l = tid & 63;
  const int mt0 = w * 2;          // this wave owns M-tiles mt0, mt0+1 (gate rows 32w..32w+31)
  const int col = l & 15;         // MFMA col (batch; 4..15 are zero padding)
  const int q = l >> 4;           // k-subgroup / C-row group
  const int u = tid & 63, g = (tid >> 6) & 3;  // update mapping (tid<256)
  const int b0 = blockIdx.x * GB;

  // ---- stage x, biases; zero the bf16 h state (cols>=4 stay zero forever) ----
  for (int i = tid; i < GB * T; i += 512) {
    ((float*)xs[0])[i] = enc_x[b0 * T + i];
    ((float*)xs[1])[i] = dec_x[b0 * T + i];
  }
  if (tid < 256) {
    bias[0][tid] = eb0[tid]; bias[1][tid] = eb1[tid]; bias[2][tid] = eb2[tid];
    bias[3][tid] = db0[tid]; bias[4][tid] = db1[tid]; bias[5][tid] = db2[tid];
  }
  for (int i = tid; i < 2 * 4 * 16 * 72 / 2; i += 512) ((unsigned*)hb)[i] = 0u;

  float cr0 = 0.f, cr1 = 0.f, cr2 = 0.f;  // cell state (update threads)
  const float fcw = fcW[u];
  const float fcbv = fcb[0];

  // ---- resident weight A-fragments: 6 mats x 2 Mtiles x 2 Kchunks x (hi,lo) = 192 regs ----
  short8 Ah[6][2][2], Al[6][2][2];
  float xwc[2][4];  // input-column weights, aligned to C/D row layout

#define BUILD(S, W)                                                           \
  _Pragma("unroll") for (int mt = 0; mt < 2; ++mt)                            \
  _Pragma("unroll") for (int kc = 0; kc < 2; ++kc)                            \
      cvt8((W) + ((mt0 + mt) * 16 + col) * 64 + kc * 32 + q * 8,              \
           Ah[S][mt][kc], Al[S][mt][kc]);

#define BUILDU(S, W, LD, OFF)                                                 \
  _Pragma("unroll") for (int mt = 0; mt < 2; ++mt)                            \
  _Pragma("unroll") for (int kc = 0; kc < 2; ++kc) {                          \
    float tw[8];                                                              \
    const float* p = (W) + ((mt0 + mt) * 16 + col) * (LD) + (OFF) + kc * 32 + q * 8; \
    _Pragma("unroll") for (int j = 0; j < 8; ++j) tw[j] = p[j];               \
    cvt8(tw, Ah[S][mt][kc], Al[S][mt][kc]);                                   \
  }

  // encoder slots: 0=Whh0 1=Wih1 2=Whh1 3=Wih2 4=Whh2
  BUILD(0, eWhh0) BUILD(1, eWih1) BUILD(2, eWhh1) BUILD(3, eWih2) BUILD(4, eWhh2)
#pragma unroll
  for (int mt = 0; mt < 2; ++mt)
#pragma unroll
    for (int r = 0; r < 4; ++r) xwc[mt][r] = eWih0[(mt0 + mt) * 16 + q * 4 + r];

  __syncthreads();

#define TRIO(S, MT, KC, BH, BL)                          \
  acc[MT] = MFMA(Ah[S][MT][KC], (BH), acc[MT]);          \
  acc[MT] = MFMA(Ah[S][MT][KC], (BL), acc[MT]);          \
  acc[MT] = MFMA(Al[S][MT][KC], (BH), acc[MT]);

#define ZST                                              \
  if (col < 4) {                                         \
    *(v4f*)&zl[col][(mt0 + 0) * 16 + q * 4] = acc[0];    \
    *(v4f*)&zl[col][(mt0 + 1) * 16 + q * 4] = acc[1];    \
  }

#define XFOLD(XSEL)                                      \
  {                                                      \
    const float xv = xs[XSEL][col & 3][t];               \
    _Pragma("unroll") for (int mt = 0; mt < 2; ++mt)     \
    _Pragma("unroll") for (int r = 0; r < 4; ++r)        \
        acc[mt][r] += xwc[mt][r] * xv;                   \
  }

// z (K-complete in regs) -> gates -> (h,c); h written back as bf16 hi/lo frags.
#define ZUPD(BROW, L, EXTRA)                                                  \
  __syncthreads();                                                            \
  if (tid < 256) {                                                            \
    const float z0 = bias[BROW][u]       + zl[g][u];                          \
    const float z1 = bias[BROW][u + 64]  + zl[g][u + 64];                     \
    const float z2 = bias[BROW][u + 128] + zl[g][u + 128];                    \
    const float z3 = bias[BROW][u + 192] + zl[g][u + 192];                    \
    const float ii = sgm(z0), ff = sgm(z1), gg = ftanh(z2), oo = sgm(z3);     \
    const float cn = ff * cr##L + ii * gg;                                    \
    cr##L = cn;                                                               \
    const float hn = oo * ftanh(cn);                                          \
    const unsigned short hh = f2bf(hn);                                       \
    const unsigned short hlo_ = f2bf(hn - bf2f(hh));                          \
    hb[0][L][g][u] = hh;                                                      \
    hb[1][L][g][u] = hlo_;                                                    \
    EXTRA                                                                     \
  }                                                                           \
  __syncthreads();

#define PH1(S, AR, XSEL, BROW, L)                                             \
  {                                                                           \
    v4f acc[2];                                                               \
    acc[0] = (v4f){0.f, 0.f, 0.f, 0.f};                                       \
    acc[1] = (v4f){0.f, 0.f, 0.f, 0.f};                                       \
    _Pragma("unroll") for (int kc = 0; kc < 2; ++kc) {                        \
      const short8 bh = *(const short8*)&hb[0][AR][col][kc * 32 + q * 8];     \
      const short8 bl = *(const short8*)&hb[1][AR][col][kc * 32 + q * 8];     \
      TRIO(S, 0, kc, bh, bl) TRIO(S, 1, kc, bh, bl)                           \
    }                                                                         \
    XFOLD(XSEL)                                                               \
    ZST                                                                       \
    ZUPD(BROW, L, )                                                           \
  }

#define PH2(SA, ARA, SB, ARB, XF, XSEL, BROW, L, EXTRA)                       \
  {                                                                           \
    v4f acc[2];                                                               \
    acc[0] = (v4f){0.f, 0.f, 0.f, 0.f};                                       \
    acc[1] = (v4f){0.f, 0.f, 0.f, 0.f};                                       \
    _Pragma("unroll") for (int kc = 0; kc < 2; ++kc) {                        \
      const short8 bha = *(const short8*)&hb[0][ARA][col][kc * 32 + q * 8];   \
      const short8 bla = *(const short8*)&hb[1][ARA][col][kc * 32 + q * 8];   \
      const short8 bhb = *(const short8*)&hb[0][ARB][col][kc * 32 + q * 8];   \
      const short8 blb = *(const short8*)&hb[1][ARB][col][kc * 32 + q * 8];   \
      TRIO(SA, 0, kc, bha, bla) TRIO(SA, 1, kc, bha, bla)                     \
      TRIO(SB, 0, kc, bhb, blb) TRIO(SB, 1, kc, bhb, blb)                     \
    }                                                                         \
    if (XF) XFOLD(XSEL)                                                       \
    ZST                                                                       \
    ZUPD(BROW, L, EXTRA)                                                      \
  }

  // ---------------- Encoder ----------------
#pragma clang loop unroll(disable)
  for (int t = 0; t < T; ++t) {
    PH1(0, 0, 0, 0, 0)                 // L0: Whh0·h0 + x·Wih0
    PH2(1, 0, 2, 1, 0, 0, 1, 1, )      // L1: Wih1·h0 + Whh1·h1
    PH2(3, 1, 4, 2, 0, 0, 2, 2, )      // L2: Wih2·h1 + Whh2·h2
  }

  // ---- rebuild fragments for decoder (slots reused; 5 = y-part of dWih0) ----
  BUILD(0, dWhh0) BUILD(1, dWih1) BUILD(2, dWhh1) BUILD(3, dWih2) BUILD(4, dWhh2)
  BUILDU(5, dWih0, 65, 1)
#pragma unroll
  for (int mt = 0; mt < 2; ++mt)
#pragma unroll
    for (int r = 0; r < 4; ++r) xwc[mt][r] = dWih0[((mt0 + mt) * 16 + q * 4 + r) * 65];

  // ---------------- Decoder ----------------
#pragma clang loop unroll(disable)
  for (int t = 0; t < T; ++t) {
    PH2(5, 3, 0, 0, 1, 1, 3, 0, )      // L0: Wih0y·yp + Whh0·h0 + x·col0
    PH2(1, 0, 2, 1, 0, 0, 4, 1, )      // L1
    PH2(3, 1, 4, 2, 0, 0, 5, 2, {      // L2 + yp write + fc
      hb[0][3][g][u] = hh;
      hb[1][3][g][u] = hlo_;
      float pr = hn * fcw;
      _Pragma("unroll") for (int o = 32; o > 0; o >>= 1)
          pr += __shfl_down(pr, o, 64);
      if (u == 0) out[(b0 + g) * T + t] = pr + fcbv;
    })
  }
#undef PH2
#undef PH1
#undef ZUPD
#undef XFOLD
#undef ZST
#undef TRIO
#undef BUILDU
#undef BUILD
}

}  // namespace

extern "C" void kernel_launch(void* const* d_in, const int* in_sizes, int n_in,
                              void* d_out, int out_size, void* d_ws, size_t ws_size,
                              hipStream_t stream) {
  const float* enc_x = (const float*)d_in[0];
  const float* dec_x = (const float*)d_in[1];
  const float* eWih0 = (const float*)d_in[2];
  const float* eWhh0 = (const float*)d_in[3];
  const float* eb0   = (const float*)d_in[4];
  const float* eWih1 = (const float*)d_in[5];
  const float* eWhh1 = (const float*)d_in[6];
  const float* eb1   = (const float*)d_in[7];
  const float* eWih2 = (const float*)d_in[8];
  const float* eWhh2 = (const float*)d_in[9];
  const float* eb2   = (const float*)d_in[10];
  const float* dWih0 = (const float*)d_in[11];
  const float* dWhh0 = (const float*)d_in[12];
  const float* db0   = (const float*)d_in[13];
  const float* dWih1 = (const float*)d_in[14];
  const float* dWhh1 = (const float*)d_in[15];
  const float* db1   = (const float*)d_in[16];
  const float* dWih2 = (const float*)d_in[17];
  const float* dWhh2 = (const float*)d_in[18];
  const float* db2   = (const float*)d_in[19];
  const float* fcW   = (const float*)d_in[20];
  const float* fcb   = (const float*)d_in[21];
  float* out = (float*)d_out;

  seq2seq_kernel<<<dim3(256), dim3(512), 0, stream>>>(
      enc_x, dec_x, eWih0, eWhh0, eb0, eWih1, eWhh1, eb1, eWih2, eWhh2, eb2,
      dWih0, dWhh0, db0, dWih1, dWhh1, db1, dWih2, dWhh2, db2, fcW, fcb, out);
}